// Round 2
// baseline (276.629 us; speedup 1.0000x reference)
//
#include <hip/hip_runtime.h>
#include <math.h>

#define N_TOTAL 40960
#define M_EV    4096
#define KNN     32
#define FEAT    192   // CIN + 2*PDIM

typedef float v2f __attribute__((ext_vector_type(2)));

__device__ __forceinline__ v2f splat2(float v) { return (v2f){v, v}; }

__device__ __forceinline__ float dot4f(float4 a, float4 b) {
    return fmaf(a.w, b.w, fmaf(a.z, b.z, fmaf(a.y, b.y, a.x * b.x)));
}

// lex-ascending bitonic sort of (d,i) across the 64 lanes of a wave
__device__ __forceinline__ void sort64(float &d, int &i, const int l)
{
#pragma unroll
    for (int k = 2; k <= 64; k <<= 1) {
#pragma unroll
        for (int j = k >> 1; j >= 1; j >>= 1) {
            float pd = __shfl_xor(d, j, 64);
            int   pi = __shfl_xor(i, j, 64);
            bool tmn  = (((l & k) == 0) == ((l & j) == 0));
            bool plt  = (pd < d) || (pd == d && pi < i);
            bool keep = tmn ? plt : !plt;
            d = keep ? pd : d;
            i = keep ? pi : i;
        }
    }
}

// ---------------------------------------------------------------------------
// Kernel 1: space = x@W_space + b_space  [N,4];  prop = x@W_prop + b_prop [N,64]
// ---------------------------------------------------------------------------
__global__ __launch_bounds__(256) void k_linear(
    const float* __restrict__ x,
    const float* __restrict__ Wp, const float* __restrict__ bp,
    const float* __restrict__ Ws, const float* __restrict__ bs,
    float* __restrict__ prop, float* __restrict__ space)
{
    __shared__ float xs[16 * 64];
    const int t = threadIdx.x;
    const int rowbase = blockIdx.x * 16;

    {
        float4 v = *(const float4*)(x + rowbase * 64 + t * 4);
        *(float4*)(xs + t * 4) = v;
    }
    __syncthreads();

    const int j  = t & 63;
    const int rg = t >> 6;
    float a0 = 0.f, a1 = 0.f, a2 = 0.f, a3 = 0.f;
#pragma unroll 8
    for (int c = 0; c < 64; ++c) {
        float w = Wp[c * 64 + j];
        a0 = fmaf(xs[(rg * 4 + 0) * 64 + c], w, a0);
        a1 = fmaf(xs[(rg * 4 + 1) * 64 + c], w, a1);
        a2 = fmaf(xs[(rg * 4 + 2) * 64 + c], w, a2);
        a3 = fmaf(xs[(rg * 4 + 3) * 64 + c], w, a3);
    }
    const float bj = bp[j];
    prop[(rowbase + rg * 4 + 0) * 64 + j] = a0 + bj;
    prop[(rowbase + rg * 4 + 1) * 64 + j] = a1 + bj;
    prop[(rowbase + rg * 4 + 2) * 64 + j] = a2 + bj;
    prop[(rowbase + rg * 4 + 3) * 64 + j] = a3 + bj;

    if (t < 64) {
        const int r = t >> 2, s = t & 3;
        float a = 0.f;
#pragma unroll 8
        for (int c = 0; c < 64; ++c)
            a = fmaf(xs[r * 64 + c], Ws[c * 4 + s], a);
        space[(rowbase + r) * 4 + s] = a + bs[s];
    }
}

// ---------------------------------------------------------------------------
// Kernel 2: exact kNN, threshold-compact-sort.
//  Round 11: packed dual-FP32 distance passes (v_pk_fma_f32).
//   * Round-10 result: QPW=8 took k_knn 112->99us, VALUBusy 60->71% ->
//     now VALU-ISSUE-bound on the scalar distance chain (2 passes x 4096
//     cand x (4 fma + 1 min) per query = ~42us of scalar VALU).
//   * This round: each lane processes TWO candidates/iter; |c|^2 and the
//     dh chain are v2f32 (ext_vector_type(2)) -> LLVM lowers to
//     v_pk_fma_f32/v_pk_mul_f32 on gfx950 (PackedFP32Ops, gfx90a+).
//     ~26 VALU issues/candidate vs 44 scalar (1.7x fewer).
//   * Numerics BITWISE IDENTICAL: packed fma == per-element fma, same
//     chain order (x,y,z,w; cc = w*w+(z*z+(y*y+x*x))) in pass1, pass2,
//     and select -> exact-compaction invariant preserved.
//   * key dh2 = |c|^2 - (2q).c  (monotone with d^2; d^2 = dh2 + |q|^2).
//   * select loop `#pragma unroll 1`; q reloaded from GLOBAL inside (the
//     round-9 alloca trap: runtime-indexed register array -> scratch).
//     qcs/mn/T only ever use constant indices.
// ---------------------------------------------------------------------------
#define QPW   8
#define QPB   32
#define TILEC 1024
#define CCAP  128

__global__ __launch_bounds__(256, 1) void k_knn(
    const float4* __restrict__ space4,
    int* __restrict__ knn_idx, float* __restrict__ knn_w,
    int* __restrict__ bad)
{
    __shared__ float4 s_c[TILEC];         // 16384 B
    __shared__ ushort s_ci[QPB * CCAP];   //  8192 B
    __shared__ int    s_cnt[QPB];         //   128 B  => 24704 B

    const int t = threadIdx.x;
    const int w = t >> 6;                 // wave 0..3
    const int l = t & 63;
    const int qb = blockIdx.x * QPB;
    const int ebase = (qb / M_EV) * M_EV;

    if (t < QPB) s_cnt[t] = 0;           // covered by first tile barrier

    float4 qcs[QPW];                      // = 2*q (doubling is exact)
#pragma unroll
    for (int s = 0; s < QPW; ++s) {
        float4 q = space4[qb + w * QPW + s];
        qcs[s] = make_float4(q.x + q.x, q.y + q.y, q.z + q.z, q.w + q.w);
    }

    float mn[QPW];
#pragma unroll
    for (int s = 0; s < QPW; ++s) mn[s] = INFINITY;

    // ---- pass 1: per-lane slice minima of dh2 (2 candidates/lane/iter) ----
#pragma unroll 1
    for (int tile = 0; tile < M_EV / TILEC; ++tile) {
        __syncthreads();
#pragma unroll
        for (int u = 0; u < TILEC / 256; ++u) {
            int ci = u * 256 + t;
            s_c[ci] = space4[ebase + tile * TILEC + ci];
        }
        __syncthreads();
#pragma unroll 2
        for (int j = 0; j < TILEC / 64; j += 2) {
            int ci = j * 64 + l;
            float4 ca = s_c[ci];
            float4 cb = s_c[ci + 64];
            v2f cx = {ca.x, cb.x}, cy = {ca.y, cb.y};
            v2f cz = {ca.z, cb.z}, cw = {ca.w, cb.w};
            v2f cc = __builtin_elementwise_fma(cw, cw,
                     __builtin_elementwise_fma(cz, cz,
                     __builtin_elementwise_fma(cy, cy, cx * cx)));
#pragma unroll
            for (int s = 0; s < QPW; ++s) {
                v2f dh = __builtin_elementwise_fma(splat2(-qcs[s].x), cx, cc);
                dh = __builtin_elementwise_fma(splat2(-qcs[s].y), cy, dh);
                dh = __builtin_elementwise_fma(splat2(-qcs[s].z), cz, dh);
                dh = __builtin_elementwise_fma(splat2(-qcs[s].w), cw, dh);
                mn[s] = fminf(mn[s], fminf(dh.x, dh.y));
            }
        }
    }

    // ---- T[s] = 32nd smallest of the 64 lane minima ----
    float v[QPW];
#pragma unroll
    for (int s = 0; s < QPW; ++s) v[s] = mn[s];
#pragma unroll
    for (int k = 2; k <= 64; k <<= 1) {
#pragma unroll
        for (int j = k >> 1; j >= 1; j >>= 1) {
            bool tmn = (((l & k) == 0) == ((l & j) == 0));
#pragma unroll
            for (int s = 0; s < QPW; ++s) {
                float p = __shfl_xor(v[s], j, 64);
                v[s] = tmn ? fminf(v[s], p) : fmaxf(v[s], p);
            }
        }
    }
    float T[QPW];
#pragma unroll
    for (int s = 0; s < QPW; ++s) T[s] = __shfl(v[s], 31, 64);

    // ---- pass 2: compact indices with dh2<=T (bitwise-identical chain) ----
#pragma unroll 1
    for (int tile = 0; tile < M_EV / TILEC; ++tile) {
        __syncthreads();
#pragma unroll
        for (int u = 0; u < TILEC / 256; ++u) {
            int ci = u * 256 + t;
            s_c[ci] = space4[ebase + tile * TILEC + ci];
        }
        __syncthreads();
#pragma unroll 2
        for (int j = 0; j < TILEC / 64; j += 2) {
            int ci = j * 64 + l;
            float4 ca = s_c[ci];
            float4 cb = s_c[ci + 64];
            v2f cx = {ca.x, cb.x}, cy = {ca.y, cb.y};
            v2f cz = {ca.z, cb.z}, cw = {ca.w, cb.w};
            v2f cc = __builtin_elementwise_fma(cw, cw,
                     __builtin_elementwise_fma(cz, cz,
                     __builtin_elementwise_fma(cy, cy, cx * cx)));
#pragma unroll
            for (int s = 0; s < QPW; ++s) {
                v2f dh = __builtin_elementwise_fma(splat2(-qcs[s].x), cx, cc);
                dh = __builtin_elementwise_fma(splat2(-qcs[s].y), cy, dh);
                dh = __builtin_elementwise_fma(splat2(-qcs[s].z), cz, dh);
                dh = __builtin_elementwise_fma(splat2(-qcs[s].w), cw, dh);
                if (dh.x <= T[s]) {
                    int p = atomicAdd(&s_cnt[w * QPW + s], 1);
                    if (p < CCAP)
                        s_ci[(w * QPW + s) * CCAP + p] = (ushort)(tile * TILEC + ci);
                }
                if (dh.y <= T[s]) {
                    int p = atomicAdd(&s_cnt[w * QPW + s], 1);
                    if (p < CCAP)
                        s_ci[(w * QPW + s) * CCAP + p] = (ushort)(tile * TILEC + ci + 64);
                }
            }
        }
    }
    // own wave wrote its own compact region; DS ops in-order per wave.

    // ---- exact select per query (unroll 1; q reloaded from global) ----
#pragma unroll 1
    for (int s = 0; s < QPW; ++s) {
        const int qi = w * QPW + s;
        const int q  = qb + qi;
        const int cnt = s_cnt[qi];                 // wave-uniform
        if (l == 0) bad[q] = (cnt > CCAP) ? 1 : 0;
        if (cnt <= CCAP) {
            float4 qo = space4[q];
            const float sqq = dot4f(qo, qo);
            const float4 qc = make_float4(qo.x + qo.x, qo.y + qo.y,
                                          qo.z + qo.z, qo.w + qo.w); // == qcs[s]

            // entry A (lanes 0..63)
            int   iA = (l < cnt) ? (int)s_ci[qi * CCAP + l] : 65535;
            float dA;
            {
                float4 c = space4[ebase + ((l < cnt) ? iA : 0)];
                float cc = dot4f(c, c);
                float dh = fmaf(-qc.x, c.x, cc);
                dh = fmaf(-qc.y, c.y, dh);
                dh = fmaf(-qc.z, c.z, dh);
                dh = fmaf(-qc.w, c.w, dh);
                dA = (l < cnt) ? dh : INFINITY;
            }

            float d; int i;
            if (cnt <= 64) {
                d = dA; i = iA;
                sort64(d, i, l);
            } else {
                // entry B (lanes 64..127)
                int   iB = (64 + l < cnt) ? (int)s_ci[qi * CCAP + 64 + l] : 65535;
                float dB;
                {
                    float4 c = space4[ebase + ((64 + l < cnt) ? iB : 0)];
                    float cc = dot4f(c, c);
                    float dh = fmaf(-qc.x, c.x, cc);
                    dh = fmaf(-qc.y, c.y, dh);
                    dh = fmaf(-qc.z, c.z, dh);
                    dh = fmaf(-qc.w, c.w, dh);
                    dB = (64 + l < cnt) ? dh : INFINITY;
                }
                sort64(dA, iA, l);
                sort64(dB, iB, l);
                // Batcher merge: concat(A, rev(B)) bitonic; lower half = lex-min
                float dBr = __shfl(dB, 63 - l, 64);
                int   iBr = __shfl(iB, 63 - l, 64);
                bool bl = (dBr < dA) || (dBr == dA && iBr < iA);
                d = bl ? dBr : dA;
                i = bl ? iBr : iA;
                // clean the bitonic lower half -> ascending
#pragma unroll
                for (int j = 32; j >= 1; j >>= 1) {
                    float pd = __shfl_xor(d, j, 64);
                    int   pi = __shfl_xor(i, j, 64);
                    bool plt  = (pd < d) || (pd == d && pi < i);
                    bool keep = ((l & j) == 0) ? plt : !plt;
                    d = keep ? pd : d;
                    i = keep ? pi : i;
                }
            }

            if (l < KNN) {
                float dt = fmaxf(d + sqq, 0.0f);   // d^2 = dh2 + |q|^2
                knn_idx[q * KNN + l] = ebase + i;
                knn_w[q * KNN + l]   = __expf(-10.0f * dt);
            }
        }
    }
}

// ---------------------------------------------------------------------------
// Kernel 2b: exact fallback for flagged queries (expected never to fire).
// ---------------------------------------------------------------------------
__global__ __launch_bounds__(256) void k_fix(
    const float4* __restrict__ space4, const int* __restrict__ bad,
    int* __restrict__ knn_idx, float* __restrict__ knn_w)
{
    const int q = blockIdx.x * 256 + threadIdx.x;
    if (!bad[q]) return;
    const int eb = (q / M_EV) * M_EV;
    float4 qc = space4[q];
    float sqq = dot4f(qc, qc);
    float ld[KNN]; int li[KNN];
    for (int e = 0; e < KNN; ++e) { ld[e] = INFINITY; li[e] = 0; }
    float cm = INFINITY; int mp = 0;
    for (int c = 0; c < M_EV; ++c) {
        float4 cc = space4[eb + c];
        float d = fmaf(-2.0f, dot4f(qc, cc), sqq + dot4f(cc, cc));
        if (d < cm) {
            ld[mp] = d; li[mp] = c;
            cm = ld[0]; mp = 0;
            for (int e = 1; e < KNN; ++e) if (ld[e] > cm) { cm = ld[e]; mp = e; }
        }
    }
    for (int e = 0; e < KNN; ++e) {
        knn_idx[q * KNN + e] = eb + li[e];
        knn_w[q * KNN + e]   = __expf(-10.0f * fmaxf(ld[e], 0.0f));
    }
}

// ---------------------------------------------------------------------------
// Kernel 3 (fused agg+out), unchanged.
// ---------------------------------------------------------------------------
#define FSTR 18

__global__ __launch_bounds__(256) void k_tail(
    const float* __restrict__ x, const float* __restrict__ prop,
    const int* __restrict__ knn_idx, const float* __restrict__ knn_w,
    const float* __restrict__ Wo, const float* __restrict__ bo,
    float* __restrict__ out)
{
    __shared__ float fs2[FEAT * FSTR];   // 13824 B
    __shared__ float s_w[48 * 128];      // 24576 B

    const int t = threadIdx.x;
    const int qb = blockIdx.x * 16;

    {
        const int r = t >> 4, c4 = (t & 15) * 4;
        float4 v = *(const float4*)(x + (size_t)(qb + r) * 64 + c4);
        fs2[(c4 + 0) * FSTR + r] = v.x;
        fs2[(c4 + 1) * FSTR + r] = v.y;
        fs2[(c4 + 2) * FSTR + r] = v.z;
        fs2[(c4 + 3) * FSTR + r] = v.w;
    }

    {
        const int p = t & 63;
#pragma unroll 1
        for (int s = 0; s < 4; ++s) {
            const int r = s * 4 + (t >> 6);
            const int q = qb + r;
            float acc = 0.f, mx = -INFINITY;
#pragma unroll 8
            for (int e = 0; e < KNN; ++e) {
                int   ix = knn_idx[q * KNN + e];
                float wv = knn_w[q * KNN + e];
                float g  = wv * prop[(size_t)ix * 64 + p];
                acc += g;
                mx = fmaxf(mx, g);
            }
            fs2[(64 + p) * FSTR + r]  = acc * (1.0f / 32.0f);
            fs2[(128 + p) * FSTR + r] = mx;
        }
    }

    const int rg = t >> 5;
    const int c4 = (t & 31) * 4;
    float acc0[4] = {0.f, 0.f, 0.f, 0.f};
    float acc1[4] = {0.f, 0.f, 0.f, 0.f};

#pragma unroll 1
    for (int cc = 0; cc < 4; ++cc) {
        __syncthreads();
#pragma unroll
        for (int u = 0; u < 6; ++u) {
            int fi = u * 1024 + t * 4;
            *(float4*)(s_w + fi) = *(const float4*)(Wo + (size_t)cc * 48 * 128 + fi);
        }
        __syncthreads();
#pragma unroll 4
        for (int ii = 0; ii < 48; ++ii) {
            int i = cc * 48 + ii;
            float2 f = *(const float2*)(fs2 + i * FSTR + rg * 2);
            float4 wv = *(const float4*)(s_w + ii * 128 + c4);
            acc0[0] = fmaf(f.x, wv.x, acc0[0]); acc0[1] = fmaf(f.x, wv.y, acc0[1]);
            acc0[2] = fmaf(f.x, wv.z, acc0[2]); acc0[3] = fmaf(f.x, wv.w, acc0[3]);
            acc1[0] = fmaf(f.y, wv.x, acc1[0]); acc1[1] = fmaf(f.y, wv.y, acc1[1]);
            acc1[2] = fmaf(f.y, wv.z, acc1[2]); acc1[3] = fmaf(f.y, wv.w, acc1[3]);
        }
    }

    const float4 bc = *(const float4*)(bo + c4);
    float4 o0, o1;
    o0.x = fmaxf(acc0[0] + bc.x, 0.f); o0.y = fmaxf(acc0[1] + bc.y, 0.f);
    o0.z = fmaxf(acc0[2] + bc.z, 0.f); o0.w = fmaxf(acc0[3] + bc.w, 0.f);
    o1.x = fmaxf(acc1[0] + bc.x, 0.f); o1.y = fmaxf(acc1[1] + bc.y, 0.f);
    o1.z = fmaxf(acc1[2] + bc.z, 0.f); o1.w = fmaxf(acc1[3] + bc.w, 0.f);
    *(float4*)(out + (size_t)(qb + rg * 2 + 0) * 128 + c4) = o0;
    *(float4*)(out + (size_t)(qb + rg * 2 + 1) * 128 + c4) = o1;
}

// ---------------------------------------------------------------------------
extern "C" void kernel_launch(void* const* d_in, const int* in_sizes, int n_in,
                              void* d_out, int out_size, void* d_ws, size_t ws_size,
                              hipStream_t stream) {
    const float* x  = (const float*)d_in[0];
    const float* Ws = (const float*)d_in[2];
    const float* bs = (const float*)d_in[3];
    const float* Wp = (const float*)d_in[4];
    const float* bp = (const float*)d_in[5];
    const float* Wo = (const float*)d_in[6];
    const float* bo = (const float*)d_in[7];
    float* out = (float*)d_out;

    float* space = (float*)d_ws;                          // N*4
    float* prop  = space + (size_t)N_TOTAL * 4;           // N*64
    int*   kidx  = (int*)(prop + (size_t)N_TOTAL * 64);   // N*32
    float* kw    = (float*)(kidx + (size_t)N_TOTAL * KNN);// N*32
    int*   bad   = (int*)(kw + (size_t)N_TOTAL * KNN);    // N

    k_linear<<<N_TOTAL / 16, 256, 0, stream>>>(x, Wp, bp, Ws, bs, prop, space);
    k_knn   <<<N_TOTAL / QPB, 256, 0, stream>>>((const float4*)space, kidx, kw, bad);
    k_fix   <<<N_TOTAL / 256, 256, 0, stream>>>((const float4*)space, bad, kidx, kw);
    k_tail  <<<N_TOTAL / 16, 256, 0, stream>>>(x, prop, kidx, kw, Wo, bo, out);
}

// Round 3
// 237.234 us; speedup vs baseline: 1.1661x; 1.1661x over previous
//
#include <hip/hip_runtime.h>
#include <math.h>

#define N_TOTAL 40960
#define M_EV    4096
#define KNN     32
#define FEAT    192   // CIN + 2*PDIM

__device__ __forceinline__ float dot4f(float4 a, float4 b) {
    return fmaf(a.w, b.w, fmaf(a.z, b.z, fmaf(a.y, b.y, a.x * b.x)));
}

// monotone float->uint key: a<b  <=>  fkey(a)<fkey(b)
__device__ __forceinline__ unsigned fkey(float f) {
    unsigned b = __float_as_uint(f);
    return b ^ ((unsigned)((int)b >> 31) | 0x80000000u);
}

// count of set bits in m at positions below this lane (64-bit mbcnt idiom)
__device__ __forceinline__ int mbcnt64(unsigned long long m) {
    return __builtin_amdgcn_mbcnt_hi((unsigned)(m >> 32),
           __builtin_amdgcn_mbcnt_lo((unsigned)m, 0u));
}

// ---------------------------------------------------------------------------
// Kernel 1: space = x@W_space + b_space  [N,4];  prop = x@W_prop + b_prop [N,64]
// ---------------------------------------------------------------------------
__global__ __launch_bounds__(256) void k_linear(
    const float* __restrict__ x,
    const float* __restrict__ Wp, const float* __restrict__ bp,
    const float* __restrict__ Ws, const float* __restrict__ bs,
    float* __restrict__ prop, float* __restrict__ space)
{
    __shared__ float xs[16 * 64];
    const int t = threadIdx.x;
    const int rowbase = blockIdx.x * 16;

    {
        float4 v = *(const float4*)(x + rowbase * 64 + t * 4);
        *(float4*)(xs + t * 4) = v;
    }
    __syncthreads();

    const int j  = t & 63;
    const int rg = t >> 6;
    float a0 = 0.f, a1 = 0.f, a2 = 0.f, a3 = 0.f;
#pragma unroll 8
    for (int c = 0; c < 64; ++c) {
        float w = Wp[c * 64 + j];
        a0 = fmaf(xs[(rg * 4 + 0) * 64 + c], w, a0);
        a1 = fmaf(xs[(rg * 4 + 1) * 64 + c], w, a1);
        a2 = fmaf(xs[(rg * 4 + 2) * 64 + c], w, a2);
        a3 = fmaf(xs[(rg * 4 + 3) * 64 + c], w, a3);
    }
    const float bj = bp[j];
    prop[(rowbase + rg * 4 + 0) * 64 + j] = a0 + bj;
    prop[(rowbase + rg * 4 + 1) * 64 + j] = a1 + bj;
    prop[(rowbase + rg * 4 + 2) * 64 + j] = a2 + bj;
    prop[(rowbase + rg * 4 + 3) * 64 + j] = a3 + bj;

    if (t < 64) {
        const int r = t >> 2, s = t & 3;
        float a = 0.f;
#pragma unroll 8
        for (int c = 0; c < 64; ++c)
            a = fmaf(xs[r * 64 + c], Ws[c * 4 + s], a);
        space[(rowbase + r) * 4 + s] = a + bs[s];
    }
}

// ---------------------------------------------------------------------------
// Kernel 2: exact kNN, threshold-compact + ballot radix-select.
//  Round 12: REVERT round-11 packed-FP32 (regressed 99->141us: v_pk_fma_f32
//   operand marshalling from b128 results cost movs, VGPR 44->64, stalls).
//   Distance passes are round-10's proven scalar form (99us, VALUBusy 71%).
//  NEW: select phase. The op output is ORDER-INVARIANT (k_tail does
//   mean/max over neighbors), so we need the exact SET of 32 (lex
//   tie-break), not a sorted list. Replace 2x sort64 + Batcher merge
//   (~49 butterfly stages = ~98 shuffles + ~245 VALU per query) with a
//   ballot radix-select on a monotone uint key:
//    * 32-step bit descent finds the exact 32nd-smallest key across the
//      <=128 compacted candidates: v_cmp+__ballot (VALU) + s_bcnt (SALU,
//      separate pipe). ZERO shuffles, ~75 VALU/query.
//    * invalid entry slots get key=UINT_MAX (never selected; no masks).
//    * ties at the boundary key (measure-zero, but exactness): rare
//      wave-uniform branch does a 13-bit index radix-select -> lowest
//      candidate indices win, preserving the lex (d,i) tie-break.
//    * selected lanes scatter-write via mbcnt prefix positions.
//   Distance chains remain BITWISE IDENTICAL in pass1/pass2/select ->
//   threshold-compaction invariant preserved.
//   key dh2 = |c|^2 - (2q).c (monotone with d^2; d^2 = dh2 + |q|^2).
//   select loop `#pragma unroll 1`; q reloaded from GLOBAL inside (the
//   round-9 alloca trap: runtime-indexed register array -> scratch).
// ---------------------------------------------------------------------------
#define QPW   8
#define QPB   32
#define TILEC 1024
#define CCAP  128

__global__ __launch_bounds__(256, 1) void k_knn(
    const float4* __restrict__ space4,
    int* __restrict__ knn_idx, float* __restrict__ knn_w,
    int* __restrict__ bad)
{
    __shared__ float4 s_c[TILEC];         // 16384 B
    __shared__ ushort s_ci[QPB * CCAP];   //  8192 B
    __shared__ int    s_cnt[QPB];         //   128 B  => 24704 B

    const int t = threadIdx.x;
    const int w = t >> 6;                 // wave 0..3
    const int l = t & 63;
    const int qb = blockIdx.x * QPB;
    const int ebase = (qb / M_EV) * M_EV;

    if (t < QPB) s_cnt[t] = 0;           // covered by first tile barrier

    float4 qcs[QPW];                      // = 2*q (doubling is exact)
#pragma unroll
    for (int s = 0; s < QPW; ++s) {
        float4 q = space4[qb + w * QPW + s];
        qcs[s] = make_float4(q.x + q.x, q.y + q.y, q.z + q.z, q.w + q.w);
    }

    float mn[QPW];
#pragma unroll
    for (int s = 0; s < QPW; ++s) mn[s] = INFINITY;

    // ---- pass 1: per-lane slice minima of dh2 ----
#pragma unroll 1
    for (int tile = 0; tile < M_EV / TILEC; ++tile) {
        __syncthreads();
#pragma unroll
        for (int u = 0; u < TILEC / 256; ++u) {
            int ci = u * 256 + t;
            s_c[ci] = space4[ebase + tile * TILEC + ci];
        }
        __syncthreads();
#pragma unroll 2
        for (int j = 0; j < TILEC / 64; ++j) {
            int ci = j * 64 + l;
            float4 c = s_c[ci];
            float cc = dot4f(c, c);
#pragma unroll
            for (int s = 0; s < QPW; ++s) {
                float dh = fmaf(-qcs[s].x, c.x, cc);
                dh = fmaf(-qcs[s].y, c.y, dh);
                dh = fmaf(-qcs[s].z, c.z, dh);
                dh = fmaf(-qcs[s].w, c.w, dh);
                mn[s] = fminf(mn[s], dh);
            }
        }
    }

    // ---- T[s] = 32nd smallest of the 64 lane minima (bitonic, 8q/stage) ----
    float v[QPW];
#pragma unroll
    for (int s = 0; s < QPW; ++s) v[s] = mn[s];
#pragma unroll
    for (int k = 2; k <= 64; k <<= 1) {
#pragma unroll
        for (int j = k >> 1; j >= 1; j >>= 1) {
            bool tmn = (((l & k) == 0) == ((l & j) == 0));
#pragma unroll
            for (int s = 0; s < QPW; ++s) {
                float p = __shfl_xor(v[s], j, 64);
                v[s] = tmn ? fminf(v[s], p) : fmaxf(v[s], p);
            }
        }
    }
    float T[QPW];
#pragma unroll
    for (int s = 0; s < QPW; ++s) T[s] = __shfl(v[s], 31, 64);

    // ---- pass 2: compact indices with dh2<=T (identical fma chain) ----
#pragma unroll 1
    for (int tile = 0; tile < M_EV / TILEC; ++tile) {
        __syncthreads();
#pragma unroll
        for (int u = 0; u < TILEC / 256; ++u) {
            int ci = u * 256 + t;
            s_c[ci] = space4[ebase + tile * TILEC + ci];
        }
        __syncthreads();
#pragma unroll 2
        for (int j = 0; j < TILEC / 64; ++j) {
            int ci = j * 64 + l;
            float4 c = s_c[ci];
            float cc = dot4f(c, c);
#pragma unroll
            for (int s = 0; s < QPW; ++s) {
                float dh = fmaf(-qcs[s].x, c.x, cc);
                dh = fmaf(-qcs[s].y, c.y, dh);
                dh = fmaf(-qcs[s].z, c.z, dh);
                dh = fmaf(-qcs[s].w, c.w, dh);
                if (dh <= T[s]) {
                    int p = atomicAdd(&s_cnt[w * QPW + s], 1);
                    if (p < CCAP)
                        s_ci[(w * QPW + s) * CCAP + p] = (ushort)(tile * TILEC + ci);
                }
            }
        }
    }
    // own wave wrote its own compact region; DS ops in-order per wave.

    // ---- exact select per query: ballot radix-select (no sorts) ----
#pragma unroll 1
    for (int s = 0; s < QPW; ++s) {
        const int qi = w * QPW + s;
        const int q  = qb + qi;
        const int cnt = s_cnt[qi];                 // wave-uniform
        if (l == 0) bad[q] = (cnt > CCAP) ? 1 : 0;
        if (cnt <= CCAP) {
            float4 qo = space4[q];
            const float sqq = dot4f(qo, qo);
            const float4 qc = make_float4(qo.x + qo.x, qo.y + qo.y,
                                          qo.z + qo.z, qo.w + qo.w); // == qcs[s]

            // entry A (slots 0..63), entry B (slots 64..127)
            const int vA = (l < cnt);
            const int vB = (64 + l < cnt);
            int iA = vA ? (int)s_ci[qi * CCAP + l] : 0;
            int iB = vB ? (int)s_ci[qi * CCAP + 64 + l] : 0;
            float dA, dB;
            {
                float4 c = space4[ebase + iA];
                float cc = dot4f(c, c);
                float dh = fmaf(-qc.x, c.x, cc);
                dh = fmaf(-qc.y, c.y, dh);
                dh = fmaf(-qc.z, c.z, dh);
                dh = fmaf(-qc.w, c.w, dh);
                dA = dh;
            }
            {
                float4 c = space4[ebase + iB];
                float cc = dot4f(c, c);
                float dh = fmaf(-qc.x, c.x, cc);
                dh = fmaf(-qc.y, c.y, dh);
                dh = fmaf(-qc.z, c.z, dh);
                dh = fmaf(-qc.w, c.w, dh);
                dB = dh;
            }
            unsigned uA = vA ? fkey(dA) : 0xFFFFFFFFu;
            unsigned uB = vB ? fkey(dB) : 0xFFFFFFFFu;

            // 32-step bit descent -> kth = exact 32nd-smallest key
            unsigned kth = 0u;
#pragma unroll
            for (int b = 31; b >= 0; --b) {
                unsigned cand = kth | (1u << b);
                int c = __popcll(__ballot(uA < cand))
                      + __popcll(__ballot(uB < cand));
                if (c < KNN) kth = cand;
            }

            unsigned long long ltA = __ballot(uA < kth);
            unsigned long long ltB = __ballot(uB < kth);
            int nLT = __popcll(ltA) + __popcll(ltB);
            int take = KNN - nLT;                  // >= 1
            unsigned long long eqA = __ballot(uA == kth);
            unsigned long long eqB = __ballot(uB == kth);
            unsigned long long sA, sB;
            if (__popcll(eqA) + __popcll(eqB) == take) {
                sA = ltA | eqA; sB = ltB | eqB;
            } else {
                // rare tie at boundary key: lowest candidate indices win
                int ki = 0;
#pragma unroll 1
                for (int b = 12; b >= 0; --b) {
                    int cand = ki | (1 << b);
                    int c = __popcll(__ballot(iA < cand) & eqA)
                          + __popcll(__ballot(iB < cand) & eqB);
                    if (c < take) ki = cand;
                }
                sA = ltA | (__ballot(iA <= ki) & eqA);
                sB = ltB | (__ballot(iB <= ki) & eqB);
            }

            // scatter-write: popc(sA)+popc(sB) == 32 exactly
            if ((sA >> l) & 1ull) {
                int pos = mbcnt64(sA);
                float dt = fmaxf(dA + sqq, 0.0f);  // d^2 = dh2 + |q|^2
                knn_idx[q * KNN + pos] = ebase + iA;
                knn_w[q * KNN + pos]   = __expf(-10.0f * dt);
            }
            if ((sB >> l) & 1ull) {
                int pos = __popcll(sA) + mbcnt64(sB);
                float dt = fmaxf(dB + sqq, 0.0f);
                knn_idx[q * KNN + pos] = ebase + iB;
                knn_w[q * KNN + pos]   = __expf(-10.0f * dt);
            }
        }
    }
}

// ---------------------------------------------------------------------------
// Kernel 2b: exact fallback for flagged queries (expected never to fire).
// ---------------------------------------------------------------------------
__global__ __launch_bounds__(256) void k_fix(
    const float4* __restrict__ space4, const int* __restrict__ bad,
    int* __restrict__ knn_idx, float* __restrict__ knn_w)
{
    const int q = blockIdx.x * 256 + threadIdx.x;
    if (!bad[q]) return;
    const int eb = (q / M_EV) * M_EV;
    float4 qc = space4[q];
    float sqq = dot4f(qc, qc);
    float ld[KNN]; int li[KNN];
    for (int e = 0; e < KNN; ++e) { ld[e] = INFINITY; li[e] = 0; }
    float cm = INFINITY; int mp = 0;
    for (int c = 0; c < M_EV; ++c) {
        float4 cc = space4[eb + c];
        float d = fmaf(-2.0f, dot4f(qc, cc), sqq + dot4f(cc, cc));
        if (d < cm) {
            ld[mp] = d; li[mp] = c;
            cm = ld[0]; mp = 0;
            for (int e = 1; e < KNN; ++e) if (ld[e] > cm) { cm = ld[e]; mp = e; }
        }
    }
    for (int e = 0; e < KNN; ++e) {
        knn_idx[q * KNN + e] = eb + li[e];
        knn_w[q * KNN + e]   = __expf(-10.0f * fmaxf(ld[e], 0.0f));
    }
}

// ---------------------------------------------------------------------------
// Kernel 3 (fused agg+out), unchanged.
// ---------------------------------------------------------------------------
#define FSTR 18

__global__ __launch_bounds__(256) void k_tail(
    const float* __restrict__ x, const float* __restrict__ prop,
    const int* __restrict__ knn_idx, const float* __restrict__ knn_w,
    const float* __restrict__ Wo, const float* __restrict__ bo,
    float* __restrict__ out)
{
    __shared__ float fs2[FEAT * FSTR];   // 13824 B
    __shared__ float s_w[48 * 128];      // 24576 B

    const int t = threadIdx.x;
    const int qb = blockIdx.x * 16;

    {
        const int r = t >> 4, c4 = (t & 15) * 4;
        float4 v = *(const float4*)(x + (size_t)(qb + r) * 64 + c4);
        fs2[(c4 + 0) * FSTR + r] = v.x;
        fs2[(c4 + 1) * FSTR + r] = v.y;
        fs2[(c4 + 2) * FSTR + r] = v.z;
        fs2[(c4 + 3) * FSTR + r] = v.w;
    }

    {
        const int p = t & 63;
#pragma unroll 1
        for (int s = 0; s < 4; ++s) {
            const int r = s * 4 + (t >> 6);
            const int q = qb + r;
            float acc = 0.f, mx = -INFINITY;
#pragma unroll 8
            for (int e = 0; e < KNN; ++e) {
                int   ix = knn_idx[q * KNN + e];
                float wv = knn_w[q * KNN + e];
                float g  = wv * prop[(size_t)ix * 64 + p];
                acc += g;
                mx = fmaxf(mx, g);
            }
            fs2[(64 + p) * FSTR + r]  = acc * (1.0f / 32.0f);
            fs2[(128 + p) * FSTR + r] = mx;
        }
    }

    const int rg = t >> 5;
    const int c4 = (t & 31) * 4;
    float acc0[4] = {0.f, 0.f, 0.f, 0.f};
    float acc1[4] = {0.f, 0.f, 0.f, 0.f};

#pragma unroll 1
    for (int cc = 0; cc < 4; ++cc) {
        __syncthreads();
#pragma unroll
        for (int u = 0; u < 6; ++u) {
            int fi = u * 1024 + t * 4;
            *(float4*)(s_w + fi) = *(const float4*)(Wo + (size_t)cc * 48 * 128 + fi);
        }
        __syncthreads();
#pragma unroll 4
        for (int ii = 0; ii < 48; ++ii) {
            int i = cc * 48 + ii;
            float2 f = *(const float2*)(fs2 + i * FSTR + rg * 2);
            float4 wv = *(const float4*)(s_w + ii * 128 + c4);
            acc0[0] = fmaf(f.x, wv.x, acc0[0]); acc0[1] = fmaf(f.x, wv.y, acc0[1]);
            acc0[2] = fmaf(f.x, wv.z, acc0[2]); acc0[3] = fmaf(f.x, wv.w, acc0[3]);
            acc1[0] = fmaf(f.y, wv.x, acc1[0]); acc1[1] = fmaf(f.y, wv.y, acc1[1]);
            acc1[2] = fmaf(f.y, wv.z, acc1[2]); acc1[3] = fmaf(f.y, wv.w, acc1[3]);
        }
    }

    const float4 bc = *(const float4*)(bo + c4);
    float4 o0, o1;
    o0.x = fmaxf(acc0[0] + bc.x, 0.f); o0.y = fmaxf(acc0[1] + bc.y, 0.f);
    o0.z = fmaxf(acc0[2] + bc.z, 0.f); o0.w = fmaxf(acc0[3] + bc.w, 0.f);
    o1.x = fmaxf(acc1[0] + bc.x, 0.f); o1.y = fmaxf(acc1[1] + bc.y, 0.f);
    o1.z = fmaxf(acc1[2] + bc.z, 0.f); o1.w = fmaxf(acc1[3] + bc.w, 0.f);
    *(float4*)(out + (size_t)(qb + rg * 2 + 0) * 128 + c4) = o0;
    *(float4*)(out + (size_t)(qb + rg * 2 + 1) * 128 + c4) = o1;
}

// ---------------------------------------------------------------------------
extern "C" void kernel_launch(void* const* d_in, const int* in_sizes, int n_in,
                              void* d_out, int out_size, void* d_ws, size_t ws_size,
                              hipStream_t stream) {
    const float* x  = (const float*)d_in[0];
    const float* Ws = (const float*)d_in[2];
    const float* bs = (const float*)d_in[3];
    const float* Wp = (const float*)d_in[4];
    const float* bp = (const float*)d_in[5];
    const float* Wo = (const float*)d_in[6];
    const float* bo = (const float*)d_in[7];
    float* out = (float*)d_out;

    float* space = (float*)d_ws;                          // N*4
    float* prop  = space + (size_t)N_TOTAL * 4;           // N*64
    int*   kidx  = (int*)(prop + (size_t)N_TOTAL * 64);   // N*32
    float* kw    = (float*)(kidx + (size_t)N_TOTAL * KNN);// N*32
    int*   bad   = (int*)(kw + (size_t)N_TOTAL * KNN);    // N

    k_linear<<<N_TOTAL / 16, 256, 0, stream>>>(x, Wp, bp, Ws, bs, prop, space);
    k_knn   <<<N_TOTAL / QPB, 256, 0, stream>>>((const float4*)space, kidx, kw, bad);
    k_fix   <<<N_TOTAL / 256, 256, 0, stream>>>((const float4*)space, bad, kidx, kw);
    k_tail  <<<N_TOTAL / 16, 256, 0, stream>>>(x, prop, kidx, kw, Wo, bo, out);
}

// Round 4
// 232.750 us; speedup vs baseline: 1.1885x; 1.0193x over previous
//
#include <hip/hip_runtime.h>
#include <math.h>

#define N_TOTAL 40960
#define M_EV    4096
#define KNN     32
#define FEAT    192   // CIN + 2*PDIM

__device__ __forceinline__ float dot4f(float4 a, float4 b) {
    return fmaf(a.w, b.w, fmaf(a.z, b.z, fmaf(a.y, b.y, a.x * b.x)));
}

// monotone float->uint key: a<b  <=>  fkey(a)<fkey(b)
__device__ __forceinline__ unsigned fkey(float f) {
    unsigned b = __float_as_uint(f);
    return b ^ ((unsigned)((int)b >> 31) | 0x80000000u);
}

// count of set bits in m at positions below this lane (64-bit mbcnt idiom)
__device__ __forceinline__ int mbcnt64(unsigned long long m) {
    return __builtin_amdgcn_mbcnt_hi((unsigned)(m >> 32),
           __builtin_amdgcn_mbcnt_lo((unsigned)m, 0u));
}

// ---------------------------------------------------------------------------
// Kernel 1: space = x@W_space + b_space  [N,4];  prop = x@W_prop + b_prop [N,64]
// ---------------------------------------------------------------------------
__global__ __launch_bounds__(256) void k_linear(
    const float* __restrict__ x,
    const float* __restrict__ Wp, const float* __restrict__ bp,
    const float* __restrict__ Ws, const float* __restrict__ bs,
    float* __restrict__ prop, float* __restrict__ space)
{
    __shared__ float xs[16 * 64];
    const int t = threadIdx.x;
    const int rowbase = blockIdx.x * 16;

    {
        float4 v = *(const float4*)(x + rowbase * 64 + t * 4);
        *(float4*)(xs + t * 4) = v;
    }
    __syncthreads();

    const int j  = t & 63;
    const int rg = t >> 6;
    float a0 = 0.f, a1 = 0.f, a2 = 0.f, a3 = 0.f;
#pragma unroll 8
    for (int c = 0; c < 64; ++c) {
        float w = Wp[c * 64 + j];
        a0 = fmaf(xs[(rg * 4 + 0) * 64 + c], w, a0);
        a1 = fmaf(xs[(rg * 4 + 1) * 64 + c], w, a1);
        a2 = fmaf(xs[(rg * 4 + 2) * 64 + c], w, a2);
        a3 = fmaf(xs[(rg * 4 + 3) * 64 + c], w, a3);
    }
    const float bj = bp[j];
    prop[(rowbase + rg * 4 + 0) * 64 + j] = a0 + bj;
    prop[(rowbase + rg * 4 + 1) * 64 + j] = a1 + bj;
    prop[(rowbase + rg * 4 + 2) * 64 + j] = a2 + bj;
    prop[(rowbase + rg * 4 + 3) * 64 + j] = a3 + bj;

    if (t < 64) {
        const int r = t >> 2, s = t & 3;
        float a = 0.f;
#pragma unroll 8
        for (int c = 0; c < 64; ++c)
            a = fmaf(xs[r * 64 + c], Ws[c * 4 + s], a);
        space[(rowbase + r) * 4 + s] = a + bs[s];
    }
}

// ---------------------------------------------------------------------------
// Kernel 2: exact kNN, threshold-compact + ballot radix-select.
//  Round 13 (on top of round-12's ballot select, 92.7us VALUBusy 73%):
//   (a) s_h is BACK: VALU is now the pole pipe (73% vs LDS ~15%), so
//       0.5|c|^2 is computed once per candidate at staging (ds_read_b32
//       on the idle LDS pipe) instead of 4 VALU per candidate per pass
//       per lane. Key reverts to round-0 form dh = 0.5|c|^2 - q.c,
//       d^2 = 2*dh + |q|^2. Chains bitwise-identical in pass1/pass2/
//       select -> exact-compaction invariant preserved.
//   (b) select loop FULLY UNROLLED (ballot select is ~300 instr/query,
//       unlike round-9's 3x sort64 which did blow I-cache): constant s
//       everywhere -> qcs[s] register-indexed (no per-query q reload),
//       16 candidate gathers hoisted/pipelined by the scheduler, and
//       the 8 serial 32-step descent chains interleave at issue level.
//   (c) __launch_bounds__(256,4): cap VGPR at 128, forbid spills. Grid
//       is 1280 blocks = 5 blocks/CU (grid-limited occupancy), so VGPR
//       up to 128 costs nothing.
// ---------------------------------------------------------------------------
#define QPW   8
#define QPB   32
#define TILEC 1024
#define CCAP  128

__global__ __launch_bounds__(256, 4) void k_knn(
    const float4* __restrict__ space4,
    int* __restrict__ knn_idx, float* __restrict__ knn_w,
    int* __restrict__ bad)
{
    __shared__ float4 s_c[TILEC];         // 16384 B
    __shared__ float  s_h[TILEC];         //  4096 B  (0.5*|c|^2)
    __shared__ ushort s_ci[QPB * CCAP];   //  8192 B
    __shared__ int    s_cnt[QPB];         //   128 B  => 28800 B (5 blk/CU ok)

    const int t = threadIdx.x;
    const int w = t >> 6;                 // wave 0..3
    const int l = t & 63;
    const int qb = blockIdx.x * QPB;
    const int ebase = (qb / M_EV) * M_EV;

    if (t < QPB) s_cnt[t] = 0;           // covered by first tile barrier

    float4 qcs[QPW];                      // plain q
#pragma unroll
    for (int s = 0; s < QPW; ++s)
        qcs[s] = space4[qb + w * QPW + s];

    float mn[QPW];
#pragma unroll
    for (int s = 0; s < QPW; ++s) mn[s] = INFINITY;

    // ---- pass 1: per-lane slice minima of dh ----
#pragma unroll 1
    for (int tile = 0; tile < M_EV / TILEC; ++tile) {
        __syncthreads();
#pragma unroll
        for (int u = 0; u < TILEC / 256; ++u) {
            int ci = u * 256 + t;
            float4 c = space4[ebase + tile * TILEC + ci];
            s_c[ci] = c;
            s_h[ci] = 0.5f * dot4f(c, c);
        }
        __syncthreads();
#pragma unroll 2
        for (int j = 0; j < TILEC / 64; ++j) {
            int ci = j * 64 + l;
            float4 c = s_c[ci]; float hc = s_h[ci];
#pragma unroll
            for (int s = 0; s < QPW; ++s) {
                float dh = fmaf(-qcs[s].x, c.x, hc);
                dh = fmaf(-qcs[s].y, c.y, dh);
                dh = fmaf(-qcs[s].z, c.z, dh);
                dh = fmaf(-qcs[s].w, c.w, dh);
                mn[s] = fminf(mn[s], dh);
            }
        }
    }

    // ---- T[s] = 32nd smallest of the 64 lane minima (bitonic, 8q/stage) ----
    float v[QPW];
#pragma unroll
    for (int s = 0; s < QPW; ++s) v[s] = mn[s];
#pragma unroll
    for (int k = 2; k <= 64; k <<= 1) {
#pragma unroll
        for (int j = k >> 1; j >= 1; j >>= 1) {
            bool tmn = (((l & k) == 0) == ((l & j) == 0));
#pragma unroll
            for (int s = 0; s < QPW; ++s) {
                float p = __shfl_xor(v[s], j, 64);
                v[s] = tmn ? fminf(v[s], p) : fmaxf(v[s], p);
            }
        }
    }
    float T[QPW];
#pragma unroll
    for (int s = 0; s < QPW; ++s) T[s] = __shfl(v[s], 31, 64);

    // ---- pass 2: compact indices with dh<=T (identical fma chain) ----
#pragma unroll 1
    for (int tile = 0; tile < M_EV / TILEC; ++tile) {
        __syncthreads();
#pragma unroll
        for (int u = 0; u < TILEC / 256; ++u) {
            int ci = u * 256 + t;
            float4 c = space4[ebase + tile * TILEC + ci];
            s_c[ci] = c;
            s_h[ci] = 0.5f * dot4f(c, c);
        }
        __syncthreads();
#pragma unroll 2
        for (int j = 0; j < TILEC / 64; ++j) {
            int ci = j * 64 + l;
            float4 c = s_c[ci]; float hc = s_h[ci];
#pragma unroll
            for (int s = 0; s < QPW; ++s) {
                float dh = fmaf(-qcs[s].x, c.x, hc);
                dh = fmaf(-qcs[s].y, c.y, dh);
                dh = fmaf(-qcs[s].z, c.z, dh);
                dh = fmaf(-qcs[s].w, c.w, dh);
                if (dh <= T[s]) {
                    int p = atomicAdd(&s_cnt[w * QPW + s], 1);
                    if (p < CCAP)
                        s_ci[(w * QPW + s) * CCAP + p] = (ushort)(tile * TILEC + ci);
                }
            }
        }
    }
    // own wave wrote its own compact region; DS ops in-order per wave.

    // ---- exact select per query: ballot radix-select, FULLY UNROLLED ----
#pragma unroll
    for (int s = 0; s < QPW; ++s) {
        const int qi = w * QPW + s;
        const int q  = qb + qi;
        const int cnt = s_cnt[qi];                 // wave-uniform
        if (l == 0) bad[q] = (cnt > CCAP) ? 1 : 0;
        if (cnt <= CCAP) {
            const float4 qc = qcs[s];              // constant index: registers
            const float sqq = dot4f(qc, qc);

            // entry A (slots 0..63), entry B (slots 64..127)
            const int vA = (l < cnt);
            const int vB = (64 + l < cnt);
            int iA = vA ? (int)s_ci[qi * CCAP + l] : 0;
            int iB = vB ? (int)s_ci[qi * CCAP + 64 + l] : 0;
            float dA, dB;
            {
                float4 c = space4[ebase + iA];
                float hc = 0.5f * dot4f(c, c);
                float dh = fmaf(-qc.x, c.x, hc);
                dh = fmaf(-qc.y, c.y, dh);
                dh = fmaf(-qc.z, c.z, dh);
                dh = fmaf(-qc.w, c.w, dh);
                dA = dh;
            }
            {
                float4 c = space4[ebase + iB];
                float hc = 0.5f * dot4f(c, c);
                float dh = fmaf(-qc.x, c.x, hc);
                dh = fmaf(-qc.y, c.y, dh);
                dh = fmaf(-qc.z, c.z, dh);
                dh = fmaf(-qc.w, c.w, dh);
                dB = dh;
            }
            unsigned uA = vA ? fkey(dA) : 0xFFFFFFFFu;
            unsigned uB = vB ? fkey(dB) : 0xFFFFFFFFu;

            // 32-step bit descent -> kth = exact 32nd-smallest key
            unsigned kth = 0u;
#pragma unroll
            for (int b = 31; b >= 0; --b) {
                unsigned cand = kth | (1u << b);
                int c = __popcll(__ballot(uA < cand))
                      + __popcll(__ballot(uB < cand));
                if (c < KNN) kth = cand;
            }

            unsigned long long ltA = __ballot(uA < kth);
            unsigned long long ltB = __ballot(uB < kth);
            int nLT = __popcll(ltA) + __popcll(ltB);
            int take = KNN - nLT;                  // >= 1
            unsigned long long eqA = __ballot(uA == kth);
            unsigned long long eqB = __ballot(uB == kth);
            unsigned long long sA, sB;
            if (__popcll(eqA) + __popcll(eqB) == take) {
                sA = ltA | eqA; sB = ltB | eqB;
            } else {
                // rare tie at boundary key: lowest candidate indices win
                int ki = 0;
#pragma unroll 1
                for (int b = 12; b >= 0; --b) {
                    int cand = ki | (1 << b);
                    int c = __popcll(__ballot(iA < cand) & eqA)
                          + __popcll(__ballot(iB < cand) & eqB);
                    if (c < take) ki = cand;
                }
                sA = ltA | (__ballot(iA <= ki) & eqA);
                sB = ltB | (__ballot(iB <= ki) & eqB);
            }

            // scatter-write: popc(sA)+popc(sB) == 32 exactly
            if ((sA >> l) & 1ull) {
                int pos = mbcnt64(sA);
                float dt = fmaxf(fmaf(2.0f, dA, sqq), 0.0f); // d^2 = 2dh + |q|^2
                knn_idx[q * KNN + pos] = ebase + iA;
                knn_w[q * KNN + pos]   = __expf(-10.0f * dt);
            }
            if ((sB >> l) & 1ull) {
                int pos = __popcll(sA) + mbcnt64(sB);
                float dt = fmaxf(fmaf(2.0f, dB, sqq), 0.0f);
                knn_idx[q * KNN + pos] = ebase + iB;
                knn_w[q * KNN + pos]   = __expf(-10.0f * dt);
            }
        }
    }
}

// ---------------------------------------------------------------------------
// Kernel 2b: exact fallback for flagged queries (expected never to fire).
// ---------------------------------------------------------------------------
__global__ __launch_bounds__(256) void k_fix(
    const float4* __restrict__ space4, const int* __restrict__ bad,
    int* __restrict__ knn_idx, float* __restrict__ knn_w)
{
    const int q = blockIdx.x * 256 + threadIdx.x;
    if (!bad[q]) return;
    const int eb = (q / M_EV) * M_EV;
    float4 qc = space4[q];
    float sqq = dot4f(qc, qc);
    float ld[KNN]; int li[KNN];
    for (int e = 0; e < KNN; ++e) { ld[e] = INFINITY; li[e] = 0; }
    float cm = INFINITY; int mp = 0;
    for (int c = 0; c < M_EV; ++c) {
        float4 cc = space4[eb + c];
        float d = fmaf(-2.0f, dot4f(qc, cc), sqq + dot4f(cc, cc));
        if (d < cm) {
            ld[mp] = d; li[mp] = c;
            cm = ld[0]; mp = 0;
            for (int e = 1; e < KNN; ++e) if (ld[e] > cm) { cm = ld[e]; mp = e; }
        }
    }
    for (int e = 0; e < KNN; ++e) {
        knn_idx[q * KNN + e] = eb + li[e];
        knn_w[q * KNN + e]   = __expf(-10.0f * fmaxf(ld[e], 0.0f));
    }
}

// ---------------------------------------------------------------------------
// Kernel 3 (fused agg+out), unchanged.
// ---------------------------------------------------------------------------
#define FSTR 18

__global__ __launch_bounds__(256) void k_tail(
    const float* __restrict__ x, const float* __restrict__ prop,
    const int* __restrict__ knn_idx, const float* __restrict__ knn_w,
    const float* __restrict__ Wo, const float* __restrict__ bo,
    float* __restrict__ out)
{
    __shared__ float fs2[FEAT * FSTR];   // 13824 B
    __shared__ float s_w[48 * 128];      // 24576 B

    const int t = threadIdx.x;
    const int qb = blockIdx.x * 16;

    {
        const int r = t >> 4, c4 = (t & 15) * 4;
        float4 v = *(const float4*)(x + (size_t)(qb + r) * 64 + c4);
        fs2[(c4 + 0) * FSTR + r] = v.x;
        fs2[(c4 + 1) * FSTR + r] = v.y;
        fs2[(c4 + 2) * FSTR + r] = v.z;
        fs2[(c4 + 3) * FSTR + r] = v.w;
    }

    {
        const int p = t & 63;
#pragma unroll 1
        for (int s = 0; s < 4; ++s) {
            const int r = s * 4 + (t >> 6);
            const int q = qb + r;
            float acc = 0.f, mx = -INFINITY;
#pragma unroll 8
            for (int e = 0; e < KNN; ++e) {
                int   ix = knn_idx[q * KNN + e];
                float wv = knn_w[q * KNN + e];
                float g  = wv * prop[(size_t)ix * 64 + p];
                acc += g;
                mx = fmaxf(mx, g);
            }
            fs2[(64 + p) * FSTR + r]  = acc * (1.0f / 32.0f);
            fs2[(128 + p) * FSTR + r] = mx;
        }
    }

    const int rg = t >> 5;
    const int c4 = (t & 31) * 4;
    float acc0[4] = {0.f, 0.f, 0.f, 0.f};
    float acc1[4] = {0.f, 0.f, 0.f, 0.f};

#pragma unroll 1
    for (int cc = 0; cc < 4; ++cc) {
        __syncthreads();
#pragma unroll
        for (int u = 0; u < 6; ++u) {
            int fi = u * 1024 + t * 4;
            *(float4*)(s_w + fi) = *(const float4*)(Wo + (size_t)cc * 48 * 128 + fi);
        }
        __syncthreads();
#pragma unroll 4
        for (int ii = 0; ii < 48; ++ii) {
            int i = cc * 48 + ii;
            float2 f = *(const float2*)(fs2 + i * FSTR + rg * 2);
            float4 wv = *(const float4*)(s_w + ii * 128 + c4);
            acc0[0] = fmaf(f.x, wv.x, acc0[0]); acc0[1] = fmaf(f.x, wv.y, acc0[1]);
            acc0[2] = fmaf(f.x, wv.z, acc0[2]); acc0[3] = fmaf(f.x, wv.w, acc0[3]);
            acc1[0] = fmaf(f.y, wv.x, acc1[0]); acc1[1] = fmaf(f.y, wv.y, acc1[1]);
            acc1[2] = fmaf(f.y, wv.z, acc1[2]); acc1[3] = fmaf(f.y, wv.w, acc1[3]);
        }
    }

    const float4 bc = *(const float4*)(bo + c4);
    float4 o0, o1;
    o0.x = fmaxf(acc0[0] + bc.x, 0.f); o0.y = fmaxf(acc0[1] + bc.y, 0.f);
    o0.z = fmaxf(acc0[2] + bc.z, 0.f); o0.w = fmaxf(acc0[3] + bc.w, 0.f);
    o1.x = fmaxf(acc1[0] + bc.x, 0.f); o1.y = fmaxf(acc1[1] + bc.y, 0.f);
    o1.z = fmaxf(acc1[2] + bc.z, 0.f); o1.w = fmaxf(acc1[3] + bc.w, 0.f);
    *(float4*)(out + (size_t)(qb + rg * 2 + 0) * 128 + c4) = o0;
    *(float4*)(out + (size_t)(qb + rg * 2 + 1) * 128 + c4) = o1;
}

// ---------------------------------------------------------------------------
extern "C" void kernel_launch(void* const* d_in, const int* in_sizes, int n_in,
                              void* d_out, int out_size, void* d_ws, size_t ws_size,
                              hipStream_t stream) {
    const float* x  = (const float*)d_in[0];
    const float* Ws = (const float*)d_in[2];
    const float* bs = (const float*)d_in[3];
    const float* Wp = (const float*)d_in[4];
    const float* bp = (const float*)d_in[5];
    const float* Wo = (const float*)d_in[6];
    const float* bo = (const float*)d_in[7];
    float* out = (float*)d_out;

    float* space = (float*)d_ws;                          // N*4
    float* prop  = space + (size_t)N_TOTAL * 4;           // N*64
    int*   kidx  = (int*)(prop + (size_t)N_TOTAL * 64);   // N*32
    float* kw    = (float*)(kidx + (size_t)N_TOTAL * KNN);// N*32
    int*   bad   = (int*)(kw + (size_t)N_TOTAL * KNN);    // N

    k_linear<<<N_TOTAL / 16, 256, 0, stream>>>(x, Wp, bp, Ws, bs, prop, space);
    k_knn   <<<N_TOTAL / QPB, 256, 0, stream>>>((const float4*)space, kidx, kw, bad);
    k_fix   <<<N_TOTAL / 256, 256, 0, stream>>>((const float4*)space, bad, kidx, kw);
    k_tail  <<<N_TOTAL / 16, 256, 0, stream>>>(x, prop, kidx, kw, Wo, bo, out);
}

// Round 5
// 225.403 us; speedup vs baseline: 1.2273x; 1.0326x over previous
//
#include <hip/hip_runtime.h>
#include <math.h>

#define N_TOTAL 40960
#define M_EV    4096
#define KNN     32
#define FEAT    192   // CIN + 2*PDIM

__device__ __forceinline__ float dot4f(float4 a, float4 b) {
    return fmaf(a.w, b.w, fmaf(a.z, b.z, fmaf(a.y, b.y, a.x * b.x)));
}

// monotone float->uint key: a<b  <=>  fkey(a)<fkey(b)
__device__ __forceinline__ unsigned fkey(float f) {
    unsigned b = __float_as_uint(f);
    return b ^ ((unsigned)((int)b >> 31) | 0x80000000u);
}

// count of set bits in m at positions below this lane (64-bit mbcnt idiom)
__device__ __forceinline__ int mbcnt64(unsigned long long m) {
    return __builtin_amdgcn_mbcnt_hi((unsigned)(m >> 32),
           __builtin_amdgcn_mbcnt_lo((unsigned)m, 0u));
}

// ---------------------------------------------------------------------------
// Kernel 1: space = x@W_space + b_space  [N,4];  prop = x@W_prop + b_prop [N,64]
// ---------------------------------------------------------------------------
__global__ __launch_bounds__(256) void k_linear(
    const float* __restrict__ x,
    const float* __restrict__ Wp, const float* __restrict__ bp,
    const float* __restrict__ Ws, const float* __restrict__ bs,
    float* __restrict__ prop, float* __restrict__ space)
{
    __shared__ float xs[16 * 64];
    const int t = threadIdx.x;
    const int rowbase = blockIdx.x * 16;

    {
        float4 v = *(const float4*)(x + rowbase * 64 + t * 4);
        *(float4*)(xs + t * 4) = v;
    }
    __syncthreads();

    const int j  = t & 63;
    const int rg = t >> 6;
    float a0 = 0.f, a1 = 0.f, a2 = 0.f, a3 = 0.f;
#pragma unroll 8
    for (int c = 0; c < 64; ++c) {
        float w = Wp[c * 64 + j];
        a0 = fmaf(xs[(rg * 4 + 0) * 64 + c], w, a0);
        a1 = fmaf(xs[(rg * 4 + 1) * 64 + c], w, a1);
        a2 = fmaf(xs[(rg * 4 + 2) * 64 + c], w, a2);
        a3 = fmaf(xs[(rg * 4 + 3) * 64 + c], w, a3);
    }
    const float bj = bp[j];
    prop[(rowbase + rg * 4 + 0) * 64 + j] = a0 + bj;
    prop[(rowbase + rg * 4 + 1) * 64 + j] = a1 + bj;
    prop[(rowbase + rg * 4 + 2) * 64 + j] = a2 + bj;
    prop[(rowbase + rg * 4 + 3) * 64 + j] = a3 + bj;

    if (t < 64) {
        const int r = t >> 2, s = t & 3;
        float a = 0.f;
#pragma unroll 8
        for (int c = 0; c < 64; ++c)
            a = fmaf(xs[r * 64 + c], Ws[c * 4 + s], a);
        space[(rowbase + r) * 4 + s] = a + bs[s];
    }
}

// ---------------------------------------------------------------------------
// Kernel 2: exact kNN, threshold-compact + ballot radix-select.
//  Round 14 (92.4us, VALUBusy 71%; per-wave budget: distance 5.6k, pass-2
//  compaction ~5k, select 2.4k instrs):
//   (a) BALLOT-COMPACTION: pass 2's per-passer LDS atomicAdd (serializing
//       same-address ds_add_rtn + p<CCAP check, ~360/wave) replaced by one
//       __ballot per (j,query): pos = cnt + mbcnt64(mask); ushort ds_write
//       for passing lanes; cnt += popc(mask) on the SCALAR pipe. cnt lives
//       in SGPRs (own wave reads it in select; no barrier needed). s_cnt
//       LDS array deleted.
//   (b) SELECT FAST PATH: avg cnt ~45 <= 64 for most queries -> wave-
//       uniform branch to an A-only descent (skip B gather, B chain, and
//       the 2nd v_cmp in all 32 descent steps).
//   Unchanged: dh = 0.5|c|^2 - q.c staged in s_h; identical fma chain in
//   pass1/pass2/select (exact-compaction invariant); d^2 = 2dh + |q|^2.
// ---------------------------------------------------------------------------
#define QPW   8
#define QPB   32
#define TILEC 1024
#define CCAP  128

__global__ __launch_bounds__(256, 4) void k_knn(
    const float4* __restrict__ space4,
    int* __restrict__ knn_idx, float* __restrict__ knn_w,
    int* __restrict__ bad)
{
    __shared__ float4 s_c[TILEC];         // 16384 B
    __shared__ float  s_h[TILEC];         //  4096 B  (0.5*|c|^2)
    __shared__ ushort s_ci[QPB * CCAP];   //  8192 B  => 28672 B

    const int t = threadIdx.x;
    const int w = t >> 6;                 // wave 0..3
    const int l = t & 63;
    const int qb = blockIdx.x * QPB;
    const int ebase = (qb / M_EV) * M_EV;

    float4 qcs[QPW];                      // plain q
#pragma unroll
    for (int s = 0; s < QPW; ++s)
        qcs[s] = space4[qb + w * QPW + s];

    float mn[QPW];
#pragma unroll
    for (int s = 0; s < QPW; ++s) mn[s] = INFINITY;

    // ---- pass 1: per-lane slice minima of dh ----
#pragma unroll 1
    for (int tile = 0; tile < M_EV / TILEC; ++tile) {
        __syncthreads();
#pragma unroll
        for (int u = 0; u < TILEC / 256; ++u) {
            int ci = u * 256 + t;
            float4 c = space4[ebase + tile * TILEC + ci];
            s_c[ci] = c;
            s_h[ci] = 0.5f * dot4f(c, c);
        }
        __syncthreads();
#pragma unroll 2
        for (int j = 0; j < TILEC / 64; ++j) {
            int ci = j * 64 + l;
            float4 c = s_c[ci]; float hc = s_h[ci];
#pragma unroll
            for (int s = 0; s < QPW; ++s) {
                float dh = fmaf(-qcs[s].x, c.x, hc);
                dh = fmaf(-qcs[s].y, c.y, dh);
                dh = fmaf(-qcs[s].z, c.z, dh);
                dh = fmaf(-qcs[s].w, c.w, dh);
                mn[s] = fminf(mn[s], dh);
            }
        }
    }

    // ---- T[s] = 32nd smallest of the 64 lane minima (bitonic, 8q/stage) ----
    float v[QPW];
#pragma unroll
    for (int s = 0; s < QPW; ++s) v[s] = mn[s];
#pragma unroll
    for (int k = 2; k <= 64; k <<= 1) {
#pragma unroll
        for (int j = k >> 1; j >= 1; j >>= 1) {
            bool tmn = (((l & k) == 0) == ((l & j) == 0));
#pragma unroll
            for (int s = 0; s < QPW; ++s) {
                float p = __shfl_xor(v[s], j, 64);
                v[s] = tmn ? fminf(v[s], p) : fmaxf(v[s], p);
            }
        }
    }
    float T[QPW];
#pragma unroll
    for (int s = 0; s < QPW; ++s) T[s] = __shfl(v[s], 31, 64);

    // ---- pass 2: ballot-compact indices with dh<=T (identical fma chain) ----
    int cw[QPW];
#pragma unroll
    for (int s = 0; s < QPW; ++s) cw[s] = 0;

#pragma unroll 1
    for (int tile = 0; tile < M_EV / TILEC; ++tile) {
        __syncthreads();
#pragma unroll
        for (int u = 0; u < TILEC / 256; ++u) {
            int ci = u * 256 + t;
            float4 c = space4[ebase + tile * TILEC + ci];
            s_c[ci] = c;
            s_h[ci] = 0.5f * dot4f(c, c);
        }
        __syncthreads();
#pragma unroll 2
        for (int j = 0; j < TILEC / 64; ++j) {
            int ci = j * 64 + l;
            float4 c = s_c[ci]; float hc = s_h[ci];
#pragma unroll
            for (int s = 0; s < QPW; ++s) {
                float dh = fmaf(-qcs[s].x, c.x, hc);
                dh = fmaf(-qcs[s].y, c.y, dh);
                dh = fmaf(-qcs[s].z, c.z, dh);
                dh = fmaf(-qcs[s].w, c.w, dh);
                bool pass = (dh <= T[s]);
                unsigned long long m = __ballot(pass);
                if (m) {
                    int pos = cw[s] + mbcnt64(m);
                    if (pass && pos < CCAP)
                        s_ci[(w * QPW + s) * CCAP + pos] =
                            (ushort)(tile * TILEC + ci);
                    cw[s] += (int)__popcll(m);
                }
            }
        }
    }
    // own wave wrote its own compact region; DS ops in-order per wave.

    // ---- exact select per query: ballot radix-select ----
#pragma unroll
    for (int s = 0; s < QPW; ++s) {
        const int qi = w * QPW + s;
        const int q  = qb + qi;
        const int cnt = cw[s];                     // wave-uniform
        if (l == 0) bad[q] = (cnt > CCAP) ? 1 : 0;
        if (cnt <= CCAP) {
            const float4 qc = qcs[s];
            const float sqq = dot4f(qc, qc);

            // entry A (slots 0..63)
            const int vA = (l < cnt);
            int iA = vA ? (int)s_ci[qi * CCAP + l] : 0;
            float dA;
            {
                float4 c = space4[ebase + iA];
                float hc = 0.5f * dot4f(c, c);
                float dh = fmaf(-qc.x, c.x, hc);
                dh = fmaf(-qc.y, c.y, dh);
                dh = fmaf(-qc.z, c.z, dh);
                dh = fmaf(-qc.w, c.w, dh);
                dA = dh;
            }
            unsigned uA = vA ? fkey(dA) : 0xFFFFFFFFu;

            unsigned long long sA, sB;
            float dB = 0.f; int iB = 0;

            if (cnt <= 64) {
                // ---- fast path: A only ----
                unsigned kth = 0u;
#pragma unroll
                for (int b = 31; b >= 0; --b) {
                    unsigned cand = kth | (1u << b);
                    int c = __popcll(__ballot(uA < cand));
                    if (c < KNN) kth = cand;
                }
                unsigned long long ltA = __ballot(uA < kth);
                int take = KNN - __popcll(ltA);    // >= 1
                unsigned long long eqA = __ballot(uA == kth);
                if (__popcll(eqA) == take) {
                    sA = ltA | eqA;
                } else {
                    int ki = 0;
#pragma unroll 1
                    for (int b = 12; b >= 0; --b) {
                        int cand = ki | (1 << b);
                        int c = __popcll(__ballot(iA < cand) & eqA);
                        if (c < take) ki = cand;
                    }
                    sA = ltA | (__ballot(iA <= ki) & eqA);
                }
                sB = 0ull;
            } else {
                // ---- full path: A + B ----
                const int vB = (64 + l < cnt);
                iB = vB ? (int)s_ci[qi * CCAP + 64 + l] : 0;
                {
                    float4 c = space4[ebase + iB];
                    float hc = 0.5f * dot4f(c, c);
                    float dh = fmaf(-qc.x, c.x, hc);
                    dh = fmaf(-qc.y, c.y, dh);
                    dh = fmaf(-qc.z, c.z, dh);
                    dh = fmaf(-qc.w, c.w, dh);
                    dB = dh;
                }
                unsigned uB = vB ? fkey(dB) : 0xFFFFFFFFu;

                unsigned kth = 0u;
#pragma unroll
                for (int b = 31; b >= 0; --b) {
                    unsigned cand = kth | (1u << b);
                    int c = __popcll(__ballot(uA < cand))
                          + __popcll(__ballot(uB < cand));
                    if (c < KNN) kth = cand;
                }
                unsigned long long ltA = __ballot(uA < kth);
                unsigned long long ltB = __ballot(uB < kth);
                int take = KNN - (__popcll(ltA) + __popcll(ltB)); // >= 1
                unsigned long long eqA = __ballot(uA == kth);
                unsigned long long eqB = __ballot(uB == kth);
                if (__popcll(eqA) + __popcll(eqB) == take) {
                    sA = ltA | eqA; sB = ltB | eqB;
                } else {
                    int ki = 0;
#pragma unroll 1
                    for (int b = 12; b >= 0; --b) {
                        int cand = ki | (1 << b);
                        int c = __popcll(__ballot(iA < cand) & eqA)
                              + __popcll(__ballot(iB < cand) & eqB);
                        if (c < take) ki = cand;
                    }
                    sA = ltA | (__ballot(iA <= ki) & eqA);
                    sB = ltB | (__ballot(iB <= ki) & eqB);
                }
            }

            // scatter-write: popc(sA)+popc(sB) == 32 exactly
            if ((sA >> l) & 1ull) {
                int pos = mbcnt64(sA);
                float dt = fmaxf(fmaf(2.0f, dA, sqq), 0.0f); // d^2 = 2dh + |q|^2
                knn_idx[q * KNN + pos] = ebase + iA;
                knn_w[q * KNN + pos]   = __expf(-10.0f * dt);
            }
            if ((sB >> l) & 1ull) {
                int pos = __popcll(sA) + mbcnt64(sB);
                float dt = fmaxf(fmaf(2.0f, dB, sqq), 0.0f);
                knn_idx[q * KNN + pos] = ebase + iB;
                knn_w[q * KNN + pos]   = __expf(-10.0f * dt);
            }
        }
    }
}

// ---------------------------------------------------------------------------
// Kernel 2b: exact fallback for flagged queries (expected never to fire).
// ---------------------------------------------------------------------------
__global__ __launch_bounds__(256) void k_fix(
    const float4* __restrict__ space4, const int* __restrict__ bad,
    int* __restrict__ knn_idx, float* __restrict__ knn_w)
{
    const int q = blockIdx.x * 256 + threadIdx.x;
    if (!bad[q]) return;
    const int eb = (q / M_EV) * M_EV;
    float4 qc = space4[q];
    float sqq = dot4f(qc, qc);
    float ld[KNN]; int li[KNN];
    for (int e = 0; e < KNN; ++e) { ld[e] = INFINITY; li[e] = 0; }
    float cm = INFINITY; int mp = 0;
    for (int c = 0; c < M_EV; ++c) {
        float4 cc = space4[eb + c];
        float d = fmaf(-2.0f, dot4f(qc, cc), sqq + dot4f(cc, cc));
        if (d < cm) {
            ld[mp] = d; li[mp] = c;
            cm = ld[0]; mp = 0;
            for (int e = 1; e < KNN; ++e) if (ld[e] > cm) { cm = ld[e]; mp = e; }
        }
    }
    for (int e = 0; e < KNN; ++e) {
        knn_idx[q * KNN + e] = eb + li[e];
        knn_w[q * KNN + e]   = __expf(-10.0f * fmaxf(ld[e], 0.0f));
    }
}

// ---------------------------------------------------------------------------
// Kernel 3 (fused agg+out). Round 14: readfirstlane on the wave-uniform row
// so the 32 knn_idx/knn_w loads per query become provably uniform -> scalar
// loads (frees VMEM issue slots + per-lane address math in the gather loop).
// ---------------------------------------------------------------------------
#define FSTR 18

__global__ __launch_bounds__(256) void k_tail(
    const float* __restrict__ x, const float* __restrict__ prop,
    const int* __restrict__ knn_idx, const float* __restrict__ knn_w,
    const float* __restrict__ Wo, const float* __restrict__ bo,
    float* __restrict__ out)
{
    __shared__ float fs2[FEAT * FSTR];   // 13824 B
    __shared__ float s_w[48 * 128];      // 24576 B

    const int t = threadIdx.x;
    const int qb = blockIdx.x * 16;

    {
        const int r = t >> 4, c4 = (t & 15) * 4;
        float4 v = *(const float4*)(x + (size_t)(qb + r) * 64 + c4);
        fs2[(c4 + 0) * FSTR + r] = v.x;
        fs2[(c4 + 1) * FSTR + r] = v.y;
        fs2[(c4 + 2) * FSTR + r] = v.z;
        fs2[(c4 + 3) * FSTR + r] = v.w;
    }

    {
        const int p = t & 63;
#pragma unroll 1
        for (int s = 0; s < 4; ++s) {
            const int r = __builtin_amdgcn_readfirstlane(s * 4 + (t >> 6));
            const int q = qb + r;
            float acc = 0.f, mx = -INFINITY;
#pragma unroll 8
            for (int e = 0; e < KNN; ++e) {
                int   ix = knn_idx[q * KNN + e];
                float wv = knn_w[q * KNN + e];
                float g  = wv * prop[(size_t)ix * 64 + p];
                acc += g;
                mx = fmaxf(mx, g);
            }
            fs2[(64 + p) * FSTR + r]  = acc * (1.0f / 32.0f);
            fs2[(128 + p) * FSTR + r] = mx;
        }
    }

    const int rg = t >> 5;
    const int c4 = (t & 31) * 4;
    float acc0[4] = {0.f, 0.f, 0.f, 0.f};
    float acc1[4] = {0.f, 0.f, 0.f, 0.f};

#pragma unroll 1
    for (int cc = 0; cc < 4; ++cc) {
        __syncthreads();
#pragma unroll
        for (int u = 0; u < 6; ++u) {
            int fi = u * 1024 + t * 4;
            *(float4*)(s_w + fi) = *(const float4*)(Wo + (size_t)cc * 48 * 128 + fi);
        }
        __syncthreads();
#pragma unroll 4
        for (int ii = 0; ii < 48; ++ii) {
            int i = cc * 48 + ii;
            float2 f = *(const float2*)(fs2 + i * FSTR + rg * 2);
            float4 wv = *(const float4*)(s_w + ii * 128 + c4);
            acc0[0] = fmaf(f.x, wv.x, acc0[0]); acc0[1] = fmaf(f.x, wv.y, acc0[1]);
            acc0[2] = fmaf(f.x, wv.z, acc0[2]); acc0[3] = fmaf(f.x, wv.w, acc0[3]);
            acc1[0] = fmaf(f.y, wv.x, acc1[0]); acc1[1] = fmaf(f.y, wv.y, acc1[1]);
            acc1[2] = fmaf(f.y, wv.z, acc1[2]); acc1[3] = fmaf(f.y, wv.w, acc1[3]);
        }
    }

    const float4 bc = *(const float4*)(bo + c4);
    float4 o0, o1;
    o0.x = fmaxf(acc0[0] + bc.x, 0.f); o0.y = fmaxf(acc0[1] + bc.y, 0.f);
    o0.z = fmaxf(acc0[2] + bc.z, 0.f); o0.w = fmaxf(acc0[3] + bc.w, 0.f);
    o1.x = fmaxf(acc1[0] + bc.x, 0.f); o1.y = fmaxf(acc1[1] + bc.y, 0.f);
    o1.z = fmaxf(acc1[2] + bc.z, 0.f); o1.w = fmaxf(acc1[3] + bc.w, 0.f);
    *(float4*)(out + (size_t)(qb + rg * 2 + 0) * 128 + c4) = o0;
    *(float4*)(out + (size_t)(qb + rg * 2 + 1) * 128 + c4) = o1;
}

// ---------------------------------------------------------------------------
extern "C" void kernel_launch(void* const* d_in, const int* in_sizes, int n_in,
                              void* d_out, int out_size, void* d_ws, size_t ws_size,
                              hipStream_t stream) {
    const float* x  = (const float*)d_in[0];
    const float* Ws = (const float*)d_in[2];
    const float* bs = (const float*)d_in[3];
    const float* Wp = (const float*)d_in[4];
    const float* bp = (const float*)d_in[5];
    const float* Wo = (const float*)d_in[6];
    const float* bo = (const float*)d_in[7];
    float* out = (float*)d_out;

    float* space = (float*)d_ws;                          // N*4
    float* prop  = space + (size_t)N_TOTAL * 4;           // N*64
    int*   kidx  = (int*)(prop + (size_t)N_TOTAL * 64);   // N*32
    float* kw    = (float*)(kidx + (size_t)N_TOTAL * KNN);// N*32
    int*   bad   = (int*)(kw + (size_t)N_TOTAL * KNN);    // N

    k_linear<<<N_TOTAL / 16, 256, 0, stream>>>(x, Wp, bp, Ws, bs, prop, space);
    k_knn   <<<N_TOTAL / QPB, 256, 0, stream>>>((const float4*)space, kidx, kw, bad);
    k_fix   <<<N_TOTAL / 256, 256, 0, stream>>>((const float4*)space, bad, kidx, kw);
    k_tail  <<<N_TOTAL / 16, 256, 0, stream>>>(x, prop, kidx, kw, Wo, bo, out);
}